// Round 6
// baseline (449.925 us; speedup 1.0000x reference)
//
#include <hip/hip_runtime.h>
#include <math.h>

// ---------------------------------------------------------------------------
// CellTypeGNN: 2x [SAGE(mean) -> LN -> GELU -> +res] -> SAGE -> GELU -> LN -> Linear
// N=50000, E=800000, D=128, DOUT(conv3)=64, classes=40.
// R5: CSR build rewritten as 3-pass MSD bucket sort with line-dense writes:
//     binA (13 buckets, dst>>12, wave-aggregated atomics) -> binB (196
//     buckets, dst>>8) -> sortC (per-bucket LDS counting sort, sequential csr
//     write, emits off/cnt). Replaces k_count/k_scan1/k_scan2/k_fill whose
//     random 4B scatters caused 16x write amplification (52.6MB for 3.2MB).
//     csr is gapped per-bucket; k_agg reads off[]+cnt[].
// ---------------------------------------------------------------------------

typedef __attribute__((ext_vector_type(8))) short bf16x8;
typedef __attribute__((ext_vector_type(4))) float f32x4;

#define CAP1 81920   // level-1 bucket capacity (expect 65536, sigma~250)
#define CAP2 6144    // level-2 bucket capacity (expect 4096,  sigma~64)
#define NB1 13       // dst>>12 : 0..12
#define NB2 196      // dst>>8  : 0..195

__device__ inline float gelu_f(float x) {
    return 0.5f * x * (1.0f + erff(x * 0.70710678118654752440f));
}

__device__ inline float wave_sum(float v) {
#pragma unroll
    for (int d = 32; d > 0; d >>= 1) v += __shfl_xor(v, d);
    return v;
}

__device__ inline ushort f2b(float f) {  // fp32 -> bf16 RNE
    uint u = __float_as_uint(f);
    u += 0x7fffu + ((u >> 16) & 1u);
    return (ushort)(u >> 16);
}

__device__ inline float b2f(ushort h) { return __uint_as_float((uint)h << 16); }

// ---------------- bucket sort CSR build ----------------
// Group the wave's lanes by 4-bit bucket id, one atomicAdd per group, ranks
// give consecutive slots -> dense staging writes.

__device__ inline void wave_scatter_pair(uint2 val, int b, int* cur, uint2* staging,
                                         int cap, bool valid) {
    unsigned long long mask = __ballot(valid);
#pragma unroll
    for (int k = 0; k < 4; ++k) {
        bool bit = (b >> k) & 1;
        unsigned long long vb = __ballot(bit);
        mask &= bit ? vb : ~vb;
    }
    if (valid) {
        const int lane = threadIdx.x & 63;
        int rank = __popcll(mask & ((1ull << lane) - 1ull));
        int leader = __ffsll((unsigned long long)mask) - 1;
        int cnt = __popcll(mask);
        int base = 0;
        if (lane == leader) base = atomicAdd(&cur[b], cnt);
        base = __shfl(base, leader);
        int pos = base + rank;
        if (pos < cap) staging[(size_t)b * cap + pos] = val;
    }
}

__global__ void k_binA(const int* __restrict__ src, const int* __restrict__ dst, int e,
                       int* __restrict__ curA, uint2* __restrict__ stg1) {
    const int t = blockIdx.x * blockDim.x + threadIdx.x;
    const int stride = gridDim.x * blockDim.x;
    for (int base = 0; base < e; base += stride) {
        int i = base + t;
        bool valid = i < e;
        int d = valid ? dst[i] : 0;
        int s = valid ? src[i] : 0;
        wave_scatter_pair(make_uint2((uint)s, (uint)d), d >> 12, curA, stg1, CAP1, valid);
    }
}

__global__ void k_binB(const uint2* __restrict__ stg1, const int* __restrict__ curA,
                       int* __restrict__ curB, uint2* __restrict__ stg2) {
    const int b1 = blockIdx.x >> 5;        // 13 buckets x 32 chunks
    const int chunk = blockIdx.x & 31;
    int cnt = curA[b1];
    if (cnt > CAP1) cnt = CAP1;
    const uint2* in = stg1 + (size_t)b1 * CAP1;
    const int t = chunk * blockDim.x + threadIdx.x;
    const int stride = 32 * blockDim.x;
    for (int base = 0; base < cnt; base += stride) {
        int i = base + t;
        bool valid = i < cnt;
        uint2 p = valid ? in[i] : make_uint2(0u, 0u);
        int b2 = (int)((p.y >> 8) & 15u);
        wave_scatter_pair(p, b2, curB + b1 * 16, stg2 + (size_t)b1 * 16 * CAP2, CAP2, valid);
    }
}

// One workgroup per level-2 bucket (256 nodes): LDS histogram -> scan -> LDS
// scatter -> sequential csr write. Emits off[node] and cnt[node].
__global__ __launch_bounds__(256) void k_sortC(const uint2* __restrict__ stg2,
                                               const int* __restrict__ curB,
                                               int* __restrict__ csr, int* __restrict__ off,
                                               int* __restrict__ cntout, int n) {
    __shared__ int hist[256];
    __shared__ int curl[256];
    __shared__ int sm[256];
    __shared__ int buf[CAP2];
    const int bk = blockIdx.x;  // 0..195
    const int node0 = bk << 8;
    const int tid = threadIdx.x;
    int ecnt = curB[bk];
    if (ecnt > CAP2) ecnt = CAP2;
    const uint2* in = stg2 + (size_t)bk * CAP2;

    hist[tid] = 0;
    __syncthreads();
    for (int i = tid; i < ecnt; i += 256) {
        atomicAdd(&hist[(int)in[i].y - node0], 1);
    }
    __syncthreads();
    int v = hist[tid];
    sm[tid] = v;
    __syncthreads();
#pragma unroll
    for (int d = 1; d < 256; d <<= 1) {
        int add = (tid >= d) ? sm[tid - d] : 0;
        __syncthreads();
        sm[tid] += add;
        __syncthreads();
    }
    int excl = sm[tid] - v;
    const int gbase = bk * CAP2;
    int node = node0 + tid;
    if (node < n) {
        off[node] = gbase + excl;
        cntout[node] = v;
    }
    curl[tid] = excl;
    __syncthreads();
    for (int i = tid; i < ecnt; i += 256) {
        uint2 p = in[i];
        int pos = atomicAdd(&curl[(int)p.y - node0], 1);
        buf[pos] = (int)p.x;
    }
    __syncthreads();
    const int total = sm[255];
    for (int i = tid; i < total; i += 256) csr[gbase + i] = buf[i];
}

// ---------------- casts ----------------

__global__ void k_cast(const float* __restrict__ in, ushort* __restrict__ out, int nvec4) {
    int t = blockIdx.x * blockDim.x + threadIdx.x;
    int stride = gridDim.x * blockDim.x;
    for (int i = t; i < nvec4; i += stride) {
        float4 v = ((const float4*)in)[i];
        ushort4 o;
        o.x = f2b(v.x);
        o.y = f2b(v.y);
        o.z = f2b(v.z);
        o.w = f2b(v.w);
        ((ushort4*)out)[i] = o;
    }
}

// Wt[c][k] = (k<KH ? Wl[k][c] : Wr[k-KH][c]); Wt is [C][2*KH] bf16.
__global__ void k_wprep(const float* __restrict__ Wl, const float* __restrict__ Wr,
                        int KH, int C, ushort* __restrict__ Wt) {
    int t = blockIdx.x * blockDim.x + threadIdx.x;
    int total = C * 2 * KH;
    if (t >= total) return;
    int c = t / (2 * KH), k = t % (2 * KH);
    float v = (k < KH) ? Wl[(size_t)k * C + c] : Wr[(size_t)(k - KH) * C + c];
    Wt[t] = f2b(v);
}

// ---------------- mean aggregation (bf16 in/out, fp32 accumulate) ----------------
// Wave per node; csr slice cached in registers, indices via __shfl, 4-deep rows.

__global__ void k_agg(const ushort* __restrict__ X, const int* __restrict__ off,
                      const int* __restrict__ cnt, const int* __restrict__ csr,
                      ushort* __restrict__ agg, int n) {
    const int wid = (blockIdx.x * blockDim.x + threadIdx.x) >> 6;
    const int lane = threadIdx.x & 63;
    const int nw = (gridDim.x * blockDim.x) >> 6;
    for (int i = wid; i < n; i += nw) {
        int s0 = off[i];
        int deg = cnt[i];
        int c = 0;
        if (lane < deg) c = csr[s0 + lane];
        float a0 = 0.f, a1 = 0.f;
        const int dcap = deg < 64 ? deg : 64;
        int t = 0;
        for (; t + 3 < dcap; t += 4) {
            int i0 = __shfl(c, t), i1 = __shfl(c, t + 1);
            int i2 = __shfl(c, t + 2), i3 = __shfl(c, t + 3);
            uint u0 = *((const uint*)(X + (size_t)i0 * 128) + lane);
            uint u1 = *((const uint*)(X + (size_t)i1 * 128) + lane);
            uint u2 = *((const uint*)(X + (size_t)i2 * 128) + lane);
            uint u3 = *((const uint*)(X + (size_t)i3 * 128) + lane);
            a0 += __uint_as_float(u0 << 16) + __uint_as_float(u1 << 16) +
                  __uint_as_float(u2 << 16) + __uint_as_float(u3 << 16);
            a1 += __uint_as_float(u0 & 0xffff0000u) + __uint_as_float(u1 & 0xffff0000u) +
                  __uint_as_float(u2 & 0xffff0000u) + __uint_as_float(u3 & 0xffff0000u);
        }
        for (; t < dcap; ++t) {
            uint u0 = *((const uint*)(X + (size_t)__shfl(c, t) * 128) + lane);
            a0 += __uint_as_float(u0 << 16);
            a1 += __uint_as_float(u0 & 0xffff0000u);
        }
        for (int tt = s0 + 64; tt < s0 + deg; ++tt) {  // rare deg>64 tail
            uint u0 = *((const uint*)(X + (size_t)csr[tt] * 128) + lane);
            a0 += __uint_as_float(u0 << 16);
            a1 += __uint_as_float(u0 & 0xffff0000u);
        }
        float inv = 1.0f / (float)(deg > 1 ? deg : 1);
        uint pk = (uint)f2b(a0 * inv) | ((uint)f2b(a1 * inv) << 16);
        *((uint*)(agg + (size_t)i * 128) + lane) = pk;
    }
}

// ---------------- MFMA SAGE GEMM (unchanged from R4) ----------------

template <int DOUT, int EPI>
__global__ __launch_bounds__(256) void k_gemm(
    const ushort* __restrict__ Agg, const ushort* __restrict__ Xb,
    const ushort* __restrict__ Xres, const ushort* __restrict__ Wt,
    const float* __restrict__ bias, const float* __restrict__ g,
    const float* __restrict__ b, ushort* __restrict__ OutB,
    float* __restrict__ OutF, int n) {
    constexpr int CT = DOUT / 64;
    const int tid = threadIdx.x;
    const int wave = tid >> 6;
    const int lane = tid & 63;
    const int l16 = lane & 15;
    const int g4 = lane >> 4;
    const int row0 = blockIdx.x * 32;

    bf16x8 bfr[CT][8];
#pragma unroll
    for (int ct = 0; ct < CT; ++ct) {
        int col = (wave * CT + ct) * 16 + l16;
        const ushort* wp = Wt + (size_t)col * 256 + g4 * 8;
#pragma unroll
        for (int ks = 0; ks < 8; ++ks) bfr[ct][ks] = *(const bf16x8*)(wp + ks * 32);
    }

    f32x4 acc[2][CT];
#pragma unroll
    for (int rt = 0; rt < 2; ++rt)
#pragma unroll
        for (int ct = 0; ct < CT; ++ct) {
            acc[rt][ct][0] = 0.f;
            acc[rt][ct][1] = 0.f;
            acc[rt][ct][2] = 0.f;
            acc[rt][ct][3] = 0.f;
        }

    int arow[2];
#pragma unroll
    for (int rt = 0; rt < 2; ++rt) {
        int r = row0 + rt * 16 + l16;
        arow[rt] = (r < n) ? r : (n - 1);
    }

#pragma unroll
    for (int ks = 0; ks < 8; ++ks) {
        const ushort* Ak = (ks < 4) ? (Agg + ks * 32) : (Xb + (ks - 4) * 32);
#pragma unroll
        for (int rt = 0; rt < 2; ++rt) {
            bf16x8 a = *(const bf16x8*)(Ak + (size_t)arow[rt] * 128 + g4 * 8);
#pragma unroll
            for (int ct = 0; ct < CT; ++ct)
                acc[rt][ct] = __builtin_amdgcn_mfma_f32_16x16x32_bf16(a, bfr[ct][ks],
                                                                      acc[rt][ct], 0, 0, 0);
        }
    }

    float biasv[CT], gv[CT], bbv[CT];
    int colv[CT];
#pragma unroll
    for (int ct = 0; ct < CT; ++ct) {
        int col = (wave * CT + ct) * 16 + l16;
        colv[ct] = col;
        biasv[ct] = bias[col];
        if (EPI == 1) {
            gv[ct] = g[col];
            bbv[ct] = b[col];
        }
    }

    if (EPI == 1) {
        __shared__ float sP[32][4];
        __shared__ float qP[32][4];
        float v[2][4][CT];
        float sv[2][4], qv[2][4];
#pragma unroll
        for (int rt = 0; rt < 2; ++rt)
#pragma unroll
            for (int reg = 0; reg < 4; ++reg) {
                float s = 0.f, q = 0.f;
#pragma unroll
                for (int ct = 0; ct < CT; ++ct) {
                    float t = acc[rt][ct][reg] + biasv[ct];
                    v[rt][reg][ct] = t;
                    s += t;
                    q += t * t;
                }
                sv[rt][reg] = s;
                qv[rt][reg] = q;
            }
#pragma unroll
        for (int m = 1; m < 16; m <<= 1)
#pragma unroll
            for (int rt = 0; rt < 2; ++rt)
#pragma unroll
                for (int reg = 0; reg < 4; ++reg) {
                    sv[rt][reg] += __shfl_xor(sv[rt][reg], m);
                    qv[rt][reg] += __shfl_xor(qv[rt][reg], m);
                }
        if (l16 == 0) {
#pragma unroll
            for (int rt = 0; rt < 2; ++rt)
#pragma unroll
                for (int reg = 0; reg < 4; ++reg) {
                    int rib = rt * 16 + g4 * 4 + reg;
                    sP[rib][wave] = sv[rt][reg];
                    qP[rib][wave] = qv[rt][reg];
                }
        }
        __syncthreads();
#pragma unroll
        for (int rt = 0; rt < 2; ++rt) {
#pragma unroll
            for (int reg = 0; reg < 4; ++reg) {
                int rib = rt * 16 + g4 * 4 + reg;
                float s = sP[rib][0] + sP[rib][1] + sP[rib][2] + sP[rib][3];
                float q = qP[rib][0] + qP[rib][1] + qP[rib][2] + qP[rib][3];
                float mu = s * (1.0f / 128.0f);
                float var = q * (1.0f / 128.0f) - mu * mu;
                float rs = rsqrtf(fmaxf(var, 0.f) + 1e-5f);
                int r = row0 + rib;
                if (r >= n) continue;
#pragma unroll
                for (int ct = 0; ct < CT; ++ct) {
                    float y = (v[rt][reg][ct] - mu) * rs * gv[ct] + bbv[ct];
                    y = gelu_f(y) + b2f(Xres[(size_t)r * 128 + colv[ct]]);
                    OutB[(size_t)r * 128 + colv[ct]] = f2b(y);
                }
            }
        }
    } else {
#pragma unroll
        for (int rt = 0; rt < 2; ++rt)
#pragma unroll
            for (int reg = 0; reg < 4; ++reg) {
                int r = row0 + rt * 16 + g4 * 4 + reg;
                if (r >= n) continue;
#pragma unroll
                for (int ct = 0; ct < CT; ++ct)
                    OutF[(size_t)r * DOUT + colv[ct]] = gelu_f(acc[rt][ct][reg] + biasv[ct]);
            }
    }
}

// ---------------- classifier ----------------

__global__ void k_cls(const float* __restrict__ X3, const float* __restrict__ g,
                      const float* __restrict__ b, const float* __restrict__ Wc,
                      const float* __restrict__ bcls, float* __restrict__ Out, int n) {
    const int wid = (blockIdx.x * blockDim.x + threadIdx.x) >> 6;
    const int lane = threadIdx.x & 63;
    const int nw = (gridDim.x * blockDim.x) >> 6;
    const int jj = lane < 40 ? lane : 0;
    for (int i = wid; i < n; i += nw) {
        float v = X3[(size_t)i * 64 + lane];
        float mu = wave_sum(v) * (1.0f / 64.0f);
        float d = v - mu;
        float var = wave_sum(d * d) * (1.0f / 64.0f);
        float y = d * rsqrtf(var + 1e-5f) * g[lane] + b[lane];
        float o = bcls[jj];
#pragma unroll 8
        for (int k = 0; k < 64; ++k) {
            float yk = __shfl(y, k);
            o = fmaf(yk, Wc[k * 40 + jj], o);
        }
        if (lane < 40) Out[(size_t)i * 40 + lane] = o;
    }
}

// ---------------------------------------------------------------------------

extern "C" void kernel_launch(void* const* d_in, const int* in_sizes, int n_in,
                              void* d_out, int out_size, void* d_ws, size_t ws_size,
                              hipStream_t stream) {
    const float* x   = (const float*)d_in[0];
    const int* ei    = (const int*)d_in[1];
    const float* Wl1 = (const float*)d_in[2];
    const float* bl1 = (const float*)d_in[3];
    const float* Wr1 = (const float*)d_in[4];
    const float* g1  = (const float*)d_in[5];
    const float* b1  = (const float*)d_in[6];
    const float* Wl2 = (const float*)d_in[7];
    const float* bl2 = (const float*)d_in[8];
    const float* Wr2 = (const float*)d_in[9];
    const float* g2  = (const float*)d_in[10];
    const float* b2  = (const float*)d_in[11];
    const float* Wl3 = (const float*)d_in[12];
    const float* bl3 = (const float*)d_in[13];
    const float* Wr3 = (const float*)d_in[14];
    const float* gc  = (const float*)d_in[15];
    const float* bc  = (const float*)d_in[16];
    const float* Wc  = (const float*)d_in[17];
    const float* bcls= (const float*)d_in[18];

    const int n = in_sizes[0] / 128;  // 50000
    const int e = in_sizes[1] / 2;    // 800000
    const int* src = ei;
    const int* dst = ei + e;

    char* w = (char*)d_ws;
    size_t o = 0;
    auto alloc = [&](size_t bytes) -> char* {
        char* p = w + o;
        o = (o + bytes + 511) & ~(size_t)511;
        return p;
    };
    int* curAB   = (int*)alloc((size_t)(NB1 + NB2) * 4);     // curA | curB
    uint2* stg1  = (uint2*)alloc((size_t)NB1 * CAP1 * 8);    // 8.5 MB
    uint2* stg2  = (uint2*)alloc((size_t)NB2 * CAP2 * 8);    // 9.6 MB
    int* csr     = (int*)alloc((size_t)NB2 * CAP2 * 4);      // 4.8 MB (gapped)
    int* off     = (int*)alloc((size_t)n * 4);
    int* cnt     = (int*)alloc((size_t)n * 4);
    ushort* xB   = (ushort*)alloc((size_t)n * 128 * 2);
    ushort* aggB = (ushort*)alloc((size_t)n * 128 * 2);
    ushort* xaB  = (ushort*)alloc((size_t)n * 128 * 2);
    ushort* xbB  = (ushort*)alloc((size_t)n * 128 * 2);
    float* x3    = (float*)alloc((size_t)n * 64 * 4);
    ushort* W1t  = (ushort*)alloc((size_t)128 * 256 * 2);
    ushort* W2t  = (ushort*)alloc((size_t)128 * 256 * 2);
    ushort* W3t  = (ushort*)alloc((size_t)64 * 256 * 2);
    (void)ws_size;

    // CSR build: 3-pass bucket sort
    hipMemsetAsync(curAB, 0, (size_t)(NB1 + NB2) * 4, stream);
    k_binA<<<1024, 256, 0, stream>>>(src, dst, e, curAB, stg1);
    k_binB<<<NB1 * 32, 256, 0, stream>>>(stg1, curAB, curAB + NB1, stg2);
    k_sortC<<<NB2, 256, 0, stream>>>(stg2, curAB + NB1, csr, off, cnt, n);

    k_cast<<<2048, 256, 0, stream>>>(x, xB, n * 128 / 4);
    k_wprep<<<(128 * 256 + 255) / 256, 256, 0, stream>>>(Wl1, Wr1, 128, 128, W1t);
    k_wprep<<<(128 * 256 + 255) / 256, 256, 0, stream>>>(Wl2, Wr2, 128, 128, W2t);
    k_wprep<<<(64 * 256 + 255) / 256, 256, 0, stream>>>(Wl3, Wr3, 128, 64, W3t);

    const int gg = (n + 31) / 32;

    // block 1
    k_agg<<<2048, 256, 0, stream>>>(xB, off, cnt, csr, aggB, n);
    k_gemm<128, 1><<<gg, 256, 0, stream>>>(aggB, xB, xB, W1t, bl1, g1, b1, xaB, nullptr, n);
    // block 2
    k_agg<<<2048, 256, 0, stream>>>(xaB, off, cnt, csr, aggB, n);
    k_gemm<128, 1><<<gg, 256, 0, stream>>>(aggB, xaB, xaB, W2t, bl2, g2, b2, xbB, nullptr, n);
    // conv_out + GELU
    k_agg<<<2048, 256, 0, stream>>>(xbB, off, cnt, csr, aggB, n);
    k_gemm<64, 2><<<gg, 256, 0, stream>>>(aggB, xbB, nullptr, W3t, bl3, nullptr, nullptr,
                                          nullptr, x3, n);
    // classifier
    k_cls<<<2048, 256, 0, stream>>>(x3, gc, bc, Wc, bcls, (float*)d_out, n);
}

// Round 7
// 272.681 us; speedup vs baseline: 1.6500x; 1.6500x over previous
//
#include <hip/hip_runtime.h>
#include <math.h>

// ---------------------------------------------------------------------------
// CellTypeGNN: 2x [SAGE(mean) -> LN -> GELU -> +res] -> SAGE -> GELU -> LN -> Linear
// N=50000, E=800000, D=128, DOUT(conv3)=64, classes=40.
// R6: CSR build with ZERO global atomics (R5's 13 contended global cursors =
//     147us XCD ping-pong). hist (per-WG LDS histogram, 196 buckets=dst>>8)
//     -> exclusive scan of 196x256 (bucket,wg) counts -> rank scatter of
//     packed (src | ldst<<16) words to exact deterministic positions ->
//     per-bucket LDS counting sort -> compact csr + off/cnt.
// ---------------------------------------------------------------------------

typedef __attribute__((ext_vector_type(8))) short bf16x8;
typedef __attribute__((ext_vector_type(4))) float f32x4;

#define NWG 256      // workgroups in hist/scat passes
#define NBK 196      // buckets: dst>>8 (196*256 = 50176 >= n)
#define CAP2 6144    // per-bucket sortC capacity (expect ~4082, sigma 64)

__device__ inline float gelu_f(float x) {
    return 0.5f * x * (1.0f + erff(x * 0.70710678118654752440f));
}

__device__ inline float wave_sum(float v) {
#pragma unroll
    for (int d = 32; d > 0; d >>= 1) v += __shfl_xor(v, d);
    return v;
}

__device__ inline ushort f2b(float f) {  // fp32 -> bf16 RNE
    uint u = __float_as_uint(f);
    u += 0x7fffu + ((u >> 16) & 1u);
    return (ushort)(u >> 16);
}

__device__ inline float b2f(ushort h) { return __uint_as_float((uint)h << 16); }

// ---------------- CSR build: hist -> scan -> scatter -> bucket sort ----------

__global__ __launch_bounds__(256) void k_hist(const int* __restrict__ dst, int e,
                                              int* __restrict__ cnts) {
    __shared__ int h[NBK];
    const int tid = threadIdx.x;
    const int wg = blockIdx.x;
    for (int i = tid; i < NBK; i += 256) h[i] = 0;
    __syncthreads();
    const int ch = (e + NWG - 1) / NWG;
    const int lo = wg * ch;
    const int hi = min(e, lo + ch);
    for (int i = lo + tid; i < hi; i += 256) atomicAdd(&h[dst[i] >> 8], 1);
    __syncthreads();
    for (int i = tid; i < NBK; i += 256) cnts[i * NWG + wg] = h[i];
}

__global__ __launch_bounds__(256) void k_scanP1(const int* __restrict__ in,
                                                int* __restrict__ out,
                                                int* __restrict__ part, int m) {
    __shared__ int sm[256];
    const int tid = threadIdx.x;
    const int base = blockIdx.x * 1024 + tid * 4;
    int4 v = make_int4(0, 0, 0, 0);
    if (base + 3 < m) {
        v = *(const int4*)(in + base);
    } else {
        if (base + 0 < m) v.x = in[base + 0];
        if (base + 1 < m) v.y = in[base + 1];
        if (base + 2 < m) v.z = in[base + 2];
        if (base + 3 < m) v.w = in[base + 3];
    }
    int s = v.x + v.y + v.z + v.w;
    sm[tid] = s;
    __syncthreads();
#pragma unroll
    for (int d = 1; d < 256; d <<= 1) {
        int add = (tid >= d) ? sm[tid - d] : 0;
        __syncthreads();
        sm[tid] += add;
        __syncthreads();
    }
    int ex = (tid ? sm[tid - 1] : 0);
    if (base + 0 < m) out[base + 0] = ex;
    ex += v.x;
    if (base + 1 < m) out[base + 1] = ex;
    ex += v.y;
    if (base + 2 < m) out[base + 2] = ex;
    ex += v.z;
    if (base + 3 < m) out[base + 3] = ex;
    if (tid == 255) part[blockIdx.x] = sm[255];
}

__global__ __launch_bounds__(256) void k_scanP2(int* __restrict__ out,
                                                const int* __restrict__ part, int m) {
    const int tid = threadIdx.x;
    const int bid = blockIdx.x;
    const int lane = tid & 63;
    int s = 0;
    for (int j = lane; j < bid; j += 64) s += part[j];
#pragma unroll
    for (int d = 32; d > 0; d >>= 1) s += __shfl_xor(s, d);
    const int i0 = bid * 1024 + tid * 4;
#pragma unroll
    for (int j = 0; j < 4; ++j) {
        int i = i0 + j;
        if (i < m) out[i] += s;
    }
}

// scatter packed (src | local_dst<<16) to exact (wg,bucket) segment positions
__global__ __launch_bounds__(256) void k_scat(const int* __restrict__ src,
                                              const int* __restrict__ dst, int e,
                                              const int* __restrict__ bases,
                                              uint* __restrict__ pairs) {
    __shared__ int cur[NBK];
    const int tid = threadIdx.x;
    const int wg = blockIdx.x;
    for (int i = tid; i < NBK; i += 256) cur[i] = bases[i * NWG + wg];
    __syncthreads();
    const int ch = (e + NWG - 1) / NWG;
    const int lo = wg * ch;
    const int hi = min(e, lo + ch);
    for (int i = lo + tid; i < hi; i += 256) {
        int d = dst[i];
        int pos = atomicAdd(&cur[d >> 8], 1);
        pairs[pos] = (uint)src[i] | ((uint)(d & 255) << 16);
    }
}

// one workgroup per bucket: LDS counting sort of its compact segment
__global__ __launch_bounds__(256) void k_sortC(const uint* __restrict__ pairs,
                                               const int* __restrict__ bases, int e,
                                               int* __restrict__ csr, int* __restrict__ off,
                                               int* __restrict__ cntout, int n) {
    __shared__ int hist[256];
    __shared__ int curl[256];
    __shared__ int sm[256];
    __shared__ int buf[CAP2];
    const int bk = blockIdx.x;
    const int tid = threadIdx.x;
    const int start = bases[bk * NWG];
    const int end = (bk == NBK - 1) ? e : bases[(bk + 1) * NWG];
    int m = end - start;
    if (m > CAP2) m = CAP2;

    hist[tid] = 0;
    __syncthreads();
    for (int i = tid; i < m; i += 256) atomicAdd(&hist[(pairs[start + i] >> 16) & 255], 1);
    __syncthreads();
    int v = hist[tid];
    sm[tid] = v;
    __syncthreads();
#pragma unroll
    for (int d = 1; d < 256; d <<= 1) {
        int add = (tid >= d) ? sm[tid - d] : 0;
        __syncthreads();
        sm[tid] += add;
        __syncthreads();
    }
    int excl = sm[tid] - v;
    int node = (bk << 8) + tid;
    if (node < n) {
        off[node] = start + excl;
        cntout[node] = v;
    }
    curl[tid] = excl;
    __syncthreads();
    for (int i = tid; i < m; i += 256) {
        uint w = pairs[start + i];
        int pos = atomicAdd(&curl[(w >> 16) & 255], 1);
        buf[pos] = (int)(w & 0xffffu);
    }
    __syncthreads();
    for (int i = tid; i < m; i += 256) csr[start + i] = buf[i];
}

// ---------------- casts ----------------

__global__ void k_cast(const float* __restrict__ in, ushort* __restrict__ out, int nvec4) {
    int t = blockIdx.x * blockDim.x + threadIdx.x;
    int stride = gridDim.x * blockDim.x;
    for (int i = t; i < nvec4; i += stride) {
        float4 v = ((const float4*)in)[i];
        ushort4 o;
        o.x = f2b(v.x);
        o.y = f2b(v.y);
        o.z = f2b(v.z);
        o.w = f2b(v.w);
        ((ushort4*)out)[i] = o;
    }
}

// Wt[c][k] = (k<KH ? Wl[k][c] : Wr[k-KH][c]); Wt is [C][2*KH] bf16.
__global__ void k_wprep(const float* __restrict__ Wl, const float* __restrict__ Wr,
                        int KH, int C, ushort* __restrict__ Wt) {
    int t = blockIdx.x * blockDim.x + threadIdx.x;
    int total = C * 2 * KH;
    if (t >= total) return;
    int c = t / (2 * KH), k = t % (2 * KH);
    float v = (k < KH) ? Wl[(size_t)k * C + c] : Wr[(size_t)(k - KH) * C + c];
    Wt[t] = f2b(v);
}

// ---------------- mean aggregation (bf16 in/out, fp32 accumulate) ----------------

__global__ void k_agg(const ushort* __restrict__ X, const int* __restrict__ off,
                      const int* __restrict__ cnt, const int* __restrict__ csr,
                      ushort* __restrict__ agg, int n) {
    const int wid = (blockIdx.x * blockDim.x + threadIdx.x) >> 6;
    const int lane = threadIdx.x & 63;
    const int nw = (gridDim.x * blockDim.x) >> 6;
    for (int i = wid; i < n; i += nw) {
        int s0 = off[i];
        int deg = cnt[i];
        int c = 0;
        if (lane < deg) c = csr[s0 + lane];
        float a0 = 0.f, a1 = 0.f;
        const int dcap = deg < 64 ? deg : 64;
        int t = 0;
        for (; t + 3 < dcap; t += 4) {
            int i0 = __shfl(c, t), i1 = __shfl(c, t + 1);
            int i2 = __shfl(c, t + 2), i3 = __shfl(c, t + 3);
            uint u0 = *((const uint*)(X + (size_t)i0 * 128) + lane);
            uint u1 = *((const uint*)(X + (size_t)i1 * 128) + lane);
            uint u2 = *((const uint*)(X + (size_t)i2 * 128) + lane);
            uint u3 = *((const uint*)(X + (size_t)i3 * 128) + lane);
            a0 += __uint_as_float(u0 << 16) + __uint_as_float(u1 << 16) +
                  __uint_as_float(u2 << 16) + __uint_as_float(u3 << 16);
            a1 += __uint_as_float(u0 & 0xffff0000u) + __uint_as_float(u1 & 0xffff0000u) +
                  __uint_as_float(u2 & 0xffff0000u) + __uint_as_float(u3 & 0xffff0000u);
        }
        for (; t < dcap; ++t) {
            uint u0 = *((const uint*)(X + (size_t)__shfl(c, t) * 128) + lane);
            a0 += __uint_as_float(u0 << 16);
            a1 += __uint_as_float(u0 & 0xffff0000u);
        }
        for (int tt = s0 + 64; tt < s0 + deg; ++tt) {  // rare deg>64 tail
            uint u0 = *((const uint*)(X + (size_t)csr[tt] * 128) + lane);
            a0 += __uint_as_float(u0 << 16);
            a1 += __uint_as_float(u0 & 0xffff0000u);
        }
        float inv = 1.0f / (float)(deg > 1 ? deg : 1);
        uint pk = (uint)f2b(a0 * inv) | ((uint)f2b(a1 * inv) << 16);
        *((uint*)(agg + (size_t)i * 128) + lane) = pk;
    }
}

// ---------------- MFMA SAGE GEMM (unchanged from R4/R5) ----------------

template <int DOUT, int EPI>
__global__ __launch_bounds__(256) void k_gemm(
    const ushort* __restrict__ Agg, const ushort* __restrict__ Xb,
    const ushort* __restrict__ Xres, const ushort* __restrict__ Wt,
    const float* __restrict__ bias, const float* __restrict__ g,
    const float* __restrict__ b, ushort* __restrict__ OutB,
    float* __restrict__ OutF, int n) {
    constexpr int CT = DOUT / 64;
    const int tid = threadIdx.x;
    const int wave = tid >> 6;
    const int lane = tid & 63;
    const int l16 = lane & 15;
    const int g4 = lane >> 4;
    const int row0 = blockIdx.x * 32;

    bf16x8 bfr[CT][8];
#pragma unroll
    for (int ct = 0; ct < CT; ++ct) {
        int col = (wave * CT + ct) * 16 + l16;
        const ushort* wp = Wt + (size_t)col * 256 + g4 * 8;
#pragma unroll
        for (int ks = 0; ks < 8; ++ks) bfr[ct][ks] = *(const bf16x8*)(wp + ks * 32);
    }

    f32x4 acc[2][CT];
#pragma unroll
    for (int rt = 0; rt < 2; ++rt)
#pragma unroll
        for (int ct = 0; ct < CT; ++ct) {
            acc[rt][ct][0] = 0.f;
            acc[rt][ct][1] = 0.f;
            acc[rt][ct][2] = 0.f;
            acc[rt][ct][3] = 0.f;
        }

    int arow[2];
#pragma unroll
    for (int rt = 0; rt < 2; ++rt) {
        int r = row0 + rt * 16 + l16;
        arow[rt] = (r < n) ? r : (n - 1);
    }

#pragma unroll
    for (int ks = 0; ks < 8; ++ks) {
        const ushort* Ak = (ks < 4) ? (Agg + ks * 32) : (Xb + (ks - 4) * 32);
#pragma unroll
        for (int rt = 0; rt < 2; ++rt) {
            bf16x8 a = *(const bf16x8*)(Ak + (size_t)arow[rt] * 128 + g4 * 8);
#pragma unroll
            for (int ct = 0; ct < CT; ++ct)
                acc[rt][ct] = __builtin_amdgcn_mfma_f32_16x16x32_bf16(a, bfr[ct][ks],
                                                                      acc[rt][ct], 0, 0, 0);
        }
    }

    float biasv[CT], gv[CT], bbv[CT];
    int colv[CT];
#pragma unroll
    for (int ct = 0; ct < CT; ++ct) {
        int col = (wave * CT + ct) * 16 + l16;
        colv[ct] = col;
        biasv[ct] = bias[col];
        if (EPI == 1) {
            gv[ct] = g[col];
            bbv[ct] = b[col];
        }
    }

    if (EPI == 1) {
        __shared__ float sP[32][4];
        __shared__ float qP[32][4];
        float v[2][4][CT];
        float sv[2][4], qv[2][4];
#pragma unroll
        for (int rt = 0; rt < 2; ++rt)
#pragma unroll
            for (int reg = 0; reg < 4; ++reg) {
                float s = 0.f, q = 0.f;
#pragma unroll
                for (int ct = 0; ct < CT; ++ct) {
                    float t = acc[rt][ct][reg] + biasv[ct];
                    v[rt][reg][ct] = t;
                    s += t;
                    q += t * t;
                }
                sv[rt][reg] = s;
                qv[rt][reg] = q;
            }
#pragma unroll
        for (int m = 1; m < 16; m <<= 1)
#pragma unroll
            for (int rt = 0; rt < 2; ++rt)
#pragma unroll
                for (int reg = 0; reg < 4; ++reg) {
                    sv[rt][reg] += __shfl_xor(sv[rt][reg], m);
                    qv[rt][reg] += __shfl_xor(qv[rt][reg], m);
                }
        if (l16 == 0) {
#pragma unroll
            for (int rt = 0; rt < 2; ++rt)
#pragma unroll
                for (int reg = 0; reg < 4; ++reg) {
                    int rib = rt * 16 + g4 * 4 + reg;
                    sP[rib][wave] = sv[rt][reg];
                    qP[rib][wave] = qv[rt][reg];
                }
        }
        __syncthreads();
#pragma unroll
        for (int rt = 0; rt < 2; ++rt) {
#pragma unroll
            for (int reg = 0; reg < 4; ++reg) {
                int rib = rt * 16 + g4 * 4 + reg;
                float s = sP[rib][0] + sP[rib][1] + sP[rib][2] + sP[rib][3];
                float q = qP[rib][0] + qP[rib][1] + qP[rib][2] + qP[rib][3];
                float mu = s * (1.0f / 128.0f);
                float var = q * (1.0f / 128.0f) - mu * mu;
                float rs = rsqrtf(fmaxf(var, 0.f) + 1e-5f);
                int r = row0 + rib;
                if (r >= n) continue;
#pragma unroll
                for (int ct = 0; ct < CT; ++ct) {
                    float y = (v[rt][reg][ct] - mu) * rs * gv[ct] + bbv[ct];
                    y = gelu_f(y) + b2f(Xres[(size_t)r * 128 + colv[ct]]);
                    OutB[(size_t)r * 128 + colv[ct]] = f2b(y);
                }
            }
        }
    } else {
#pragma unroll
        for (int rt = 0; rt < 2; ++rt)
#pragma unroll
            for (int reg = 0; reg < 4; ++reg) {
                int r = row0 + rt * 16 + g4 * 4 + reg;
                if (r >= n) continue;
#pragma unroll
                for (int ct = 0; ct < CT; ++ct)
                    OutF[(size_t)r * DOUT + colv[ct]] = gelu_f(acc[rt][ct][reg] + biasv[ct]);
            }
    }
}

// ---------------- classifier ----------------

__global__ void k_cls(const float* __restrict__ X3, const float* __restrict__ g,
                      const float* __restrict__ b, const float* __restrict__ Wc,
                      const float* __restrict__ bcls, float* __restrict__ Out, int n) {
    const int wid = (blockIdx.x * blockDim.x + threadIdx.x) >> 6;
    const int lane = threadIdx.x & 63;
    const int nw = (gridDim.x * blockDim.x) >> 6;
    const int jj = lane < 40 ? lane : 0;
    for (int i = wid; i < n; i += nw) {
        float v = X3[(size_t)i * 64 + lane];
        float mu = wave_sum(v) * (1.0f / 64.0f);
        float d = v - mu;
        float var = wave_sum(d * d) * (1.0f / 64.0f);
        float y = d * rsqrtf(var + 1e-5f) * g[lane] + b[lane];
        float o = bcls[jj];
#pragma unroll 8
        for (int k = 0; k < 64; ++k) {
            float yk = __shfl(y, k);
            o = fmaf(yk, Wc[k * 40 + jj], o);
        }
        if (lane < 40) Out[(size_t)i * 40 + lane] = o;
    }
}

// ---------------------------------------------------------------------------

extern "C" void kernel_launch(void* const* d_in, const int* in_sizes, int n_in,
                              void* d_out, int out_size, void* d_ws, size_t ws_size,
                              hipStream_t stream) {
    const float* x   = (const float*)d_in[0];
    const int* ei    = (const int*)d_in[1];
    const float* Wl1 = (const float*)d_in[2];
    const float* bl1 = (const float*)d_in[3];
    const float* Wr1 = (const float*)d_in[4];
    const float* g1  = (const float*)d_in[5];
    const float* b1  = (const float*)d_in[6];
    const float* Wl2 = (const float*)d_in[7];
    const float* bl2 = (const float*)d_in[8];
    const float* Wr2 = (const float*)d_in[9];
    const float* g2  = (const float*)d_in[10];
    const float* b2  = (const float*)d_in[11];
    const float* Wl3 = (const float*)d_in[12];
    const float* bl3 = (const float*)d_in[13];
    const float* Wr3 = (const float*)d_in[14];
    const float* gc  = (const float*)d_in[15];
    const float* bc  = (const float*)d_in[16];
    const float* Wc  = (const float*)d_in[17];
    const float* bcls= (const float*)d_in[18];

    const int n = in_sizes[0] / 128;  // 50000
    const int e = in_sizes[1] / 2;    // 800000
    const int* src = ei;
    const int* dst = ei + e;

    char* w = (char*)d_ws;
    size_t o = 0;
    auto alloc = [&](size_t bytes) -> char* {
        char* p = w + o;
        o = (o + bytes + 511) & ~(size_t)511;
        return p;
    };
    int* cnts    = (int*)alloc((size_t)NBK * NWG * 4);  // 200 KB
    int* bases   = (int*)alloc((size_t)NBK * NWG * 4);
    int* part    = (int*)alloc(256 * 4);
    uint* pairs  = (uint*)alloc((size_t)e * 4);         // 3.2 MB
    int* csr     = (int*)alloc((size_t)e * 4);          // 3.2 MB compact
    int* off     = (int*)alloc((size_t)n * 4);
    int* cnt     = (int*)alloc((size_t)n * 4);
    ushort* xB   = (ushort*)alloc((size_t)n * 128 * 2);
    ushort* aggB = (ushort*)alloc((size_t)n * 128 * 2);
    ushort* xaB  = (ushort*)alloc((size_t)n * 128 * 2);
    ushort* xbB  = (ushort*)alloc((size_t)n * 128 * 2);
    float* x3    = (float*)alloc((size_t)n * 64 * 4);
    ushort* W1t  = (ushort*)alloc((size_t)128 * 256 * 2);
    ushort* W2t  = (ushort*)alloc((size_t)128 * 256 * 2);
    ushort* W3t  = (ushort*)alloc((size_t)64 * 256 * 2);
    (void)ws_size;

    // CSR build: hist -> scan -> scatter -> per-bucket sort (no global atomics)
    const int m = NBK * NWG;              // 50176
    const int sblk = (m + 1023) / 1024;   // 49
    k_hist<<<NWG, 256, 0, stream>>>(dst, e, cnts);
    k_scanP1<<<sblk, 256, 0, stream>>>(cnts, bases, part, m);
    k_scanP2<<<sblk, 256, 0, stream>>>(bases, part, m);
    k_scat<<<NWG, 256, 0, stream>>>(src, dst, e, bases, pairs);
    k_sortC<<<NBK, 256, 0, stream>>>(pairs, bases, e, csr, off, cnt, n);

    k_cast<<<2048, 256, 0, stream>>>(x, xB, n * 128 / 4);
    k_wprep<<<(128 * 256 + 255) / 256, 256, 0, stream>>>(Wl1, Wr1, 128, 128, W1t);
    k_wprep<<<(128 * 256 + 255) / 256, 256, 0, stream>>>(Wl2, Wr2, 128, 128, W2t);
    k_wprep<<<(64 * 256 + 255) / 256, 256, 0, stream>>>(Wl3, Wr3, 128, 64, W3t);

    const int gg = (n + 31) / 32;

    // block 1
    k_agg<<<2048, 256, 0, stream>>>(xB, off, cnt, csr, aggB, n);
    k_gemm<128, 1><<<gg, 256, 0, stream>>>(aggB, xB, xB, W1t, bl1, g1, b1, xaB, nullptr, n);
    // block 2
    k_agg<<<2048, 256, 0, stream>>>(xaB, off, cnt, csr, aggB, n);
    k_gemm<128, 1><<<gg, 256, 0, stream>>>(aggB, xaB, xaB, W2t, bl2, g2, b2, xbB, nullptr, n);
    // conv_out + GELU
    k_agg<<<2048, 256, 0, stream>>>(xbB, off, cnt, csr, aggB, n);
    k_gemm<64, 2><<<gg, 256, 0, stream>>>(aggB, xbB, nullptr, W3t, bl3, nullptr, nullptr,
                                          nullptr, x3, n);
    // classifier
    k_cls<<<2048, 256, 0, stream>>>(x3, gc, bc, Wc, bcls, (float*)d_out, n);
}